// Round 8
// baseline (725.619 us; speedup 1.0000x reference)
//
#include <hip/hip_runtime.h>

#define NN 50000
#define EE 800000
#define HD 256
#define NSEG (2 * NN)
#define CHUNK 2048
#define NB ((NSEG + CHUNK - 1) / CHUNK)

typedef unsigned short u16;
typedef short bf16x8 __attribute__((ext_vector_type(8)));
typedef float f32x4 __attribute__((ext_vector_type(4)));

__device__ __forceinline__ u16 f2bf_rne(float f) {
    unsigned u = __float_as_uint(f);
    return (u16)((u + 0x7FFF + ((u >> 16) & 1)) >> 16);
}
// trunc hi + RNE residual: (h,l) represents v to ~2^-17 relative
__device__ __forceinline__ void split_tr(float v, u16& h, u16& l) {
    unsigned u = __float_as_uint(v);
    h = (u16)(u >> 16);
    l = f2bf_rne(v - __uint_as_float(u & 0xFFFF0000u));
}

// bijective XCD-chunked swizzle (m204)
__device__ __forceinline__ int xcd_swizzle(int orig, int nwg) {
    int q = nwg >> 3, r = nwg & 7;
    int xcd = orig & 7, idx = orig >> 3;
    return (xcd < r ? xcd * (q + 1) : r * (q + 1) + (xcd - r) * q) + idx;
}

// async global->LDS, 16B per lane; LDS dest = wave-uniform base + lane*16
__device__ __forceinline__ void g2l16(const void* g, void* l) {
    __builtin_amdgcn_global_load_lds(
        (const __attribute__((address_space(1))) void*)g,
        (__attribute__((address_space(3))) void*)l, 16, 0, 0);
}

// bank swizzle for 64B-row bf16 tiles
__device__ __forceinline__ int swz2(int row) { return (row & 2) | ((row >> 2) & 1); }

// stage one 128x32 bf16 tile from G[rc][K] (k-contiguous), source-swizzled
__device__ __forceinline__ void stage_bf16(const u16* __restrict__ G, u16* S,
                                           int base_rc, int maxrc, int K, int k0, int tid) {
#pragma unroll
    for (int s = 0; s < 2; s++) {
        int slot = tid + s * 256;
        int row = slot >> 2, gg = slot & 3;
        int gsrc = gg ^ swz2(row);
        int arow = base_rc + row; arow = arow < maxrc ? arow : maxrc - 1;
        g2l16(G + (size_t)arow * K + k0 + gsrc * 8, S + ((tid & ~63) + s * 256) * 8);
    }
}

// ============ double-buffered bf16 GEMM: A hi/lo pair [M][256], B bf16 [Ncol][256] ====
// acc = Ah*Bh + Al*Bh (weights RNE bf16; activation pair exact).
// BM=BN=128, 4 waves 2x2, MFMA 16x16x32, k-map k=k0+g*8+j for both operands.
// MODE 1: lrelu -> bf16 pair out (w_in). MODE 2: relu; col<512 -> bf16 hrel; else f32 O2.
template<int MODE>
__global__ __launch_bounds__(256) void gemm_bf16L(
    const u16* __restrict__ Ahg, const u16* __restrict__ Alg,
    const u16* __restrict__ Bhg,
    const float* __restrict__ bias,
    u16* __restrict__ O1h, u16* __restrict__ O1l, float* __restrict__ O2,
    int M, int nxb)
{
    __shared__ __align__(16) u16 sAh[2][128 * 32];
    __shared__ __align__(16) u16 sAl[2][128 * 32];
    __shared__ __align__(16) u16 sBh[2][128 * 32];
    const int wgid = xcd_swizzle(blockIdx.x, gridDim.x);
    const int brow = (wgid / nxb) * 128, bcol = (wgid % nxb) * 128;
    const int tid = threadIdx.x, lane = tid & 63, w = tid >> 6;
    const int wr = w >> 1, wc = w & 1;
    const int r15 = lane & 15, g = lane >> 4;
    const int fsw = (g ^ swz2(r15)) * 8;

    f32x4 acc[4][4];
#pragma unroll
    for (int mi = 0; mi < 4; mi++)
#pragma unroll
        for (int ni = 0; ni < 4; ni++) acc[mi][ni] = (f32x4){0.f, 0.f, 0.f, 0.f};

    auto stage_step = [&](int k0, int b) {
        stage_bf16(Ahg, sAh[b], brow, M, 256, k0, tid);
        stage_bf16(Alg, sAl[b], brow, M, 256, k0, tid);
        stage_bf16(Bhg, sBh[b], bcol, 1 << 30, 256, k0, tid);
    };
    auto compute_step = [&](int b) {
        bf16x8 afh[4], afl[4], bfh[4];
#pragma unroll
        for (int mi = 0; mi < 4; mi++) {
            int idx = (wr * 64 + mi * 16 + r15) * 32 + fsw;
            afh[mi] = *(const bf16x8*)&sAh[b][idx];
            afl[mi] = *(const bf16x8*)&sAl[b][idx];
        }
#pragma unroll
        for (int ni = 0; ni < 4; ni++) {
            int idx = (wc * 64 + ni * 16 + r15) * 32 + fsw;
            bfh[ni] = *(const bf16x8*)&sBh[b][idx];
        }
#pragma unroll
        for (int mi = 0; mi < 4; mi++)
#pragma unroll
            for (int ni = 0; ni < 4; ni++)
                acc[mi][ni] = __builtin_amdgcn_mfma_f32_16x16x32_bf16(afh[mi], bfh[ni], acc[mi][ni], 0, 0, 0);
#pragma unroll
        for (int mi = 0; mi < 4; mi++)
#pragma unroll
            for (int ni = 0; ni < 4; ni++)
                acc[mi][ni] = __builtin_amdgcn_mfma_f32_16x16x32_bf16(afl[mi], bfh[ni], acc[mi][ni], 0, 0, 0);
    };

    stage_step(0, 0);
    __syncthreads();                 // buf0 staged & visible
#pragma unroll 2
    for (int t = 0; t < 7; t++) {
        stage_step((t + 1) * 32, (t + 1) & 1);   // issue next-tile loads first
        compute_step(t & 1);                      // ds_read + MFMA on current
        __syncthreads();             // drains stage(t+1); current buf free to overwrite
    }
    compute_step(1);

#pragma unroll
    for (int mi = 0; mi < 4; mi++) {
#pragma unroll
        for (int ni = 0; ni < 4; ni++) {
            int col = bcol + wc * 64 + ni * 16 + r15;
            float bsv = bias[col & (HD - 1)];
            int rbase = brow + wr * 64 + mi * 16 + g * 4;
#pragma unroll
            for (int r = 0; r < 4; r++) {
                int grow = rbase + r;
                if (grow >= M) continue;
                float v = acc[mi][ni][r] + bsv;
                if (MODE == 1) {
                    v = v > 0.f ? v : 0.01f * v;   // lrelu
                    u16 h, l; split_tr(v, h, l);
                    O1h[(size_t)grow * HD + col] = h;
                    O1l[(size_t)grow * HD + col] = l;
                } else {
                    v = fmaxf(v, 0.f);             // relu
                    if (col < 2 * HD) {
                        O1h[((size_t)(col >> 8) * NN + grow) * HD + (col & (HD - 1))] = f2bf_rne(v);
                    } else {
                        O2[(size_t)grow * HD + (col & (HD - 1))] = v;
                    }
                }
            }
        }
    }
}

// ============ double-buffered f32-A GEMM (K=768 projections) ============
// A f32 [M][768] staged raw, split hi/lo in-register. B bf16 [64][768].
// BM=128, BN=64, 4 waves 2x2 (MI=4, NI=2). acc = Ah*B + Al*B. lrelu, bf16-pair out.
__global__ __launch_bounds__(256) void gemm_f32L(
    const float* __restrict__ A,
    const u16* __restrict__ Bhg,
    const float* __restrict__ bias,
    u16* __restrict__ Ch, u16* __restrict__ Cl, int coff, int M)
{
    __shared__ __align__(16) float sA[2][128 * 32];
    __shared__ __align__(16) u16 sBh[2][64 * 32];
    const int wgid = xcd_swizzle(blockIdx.x, gridDim.x);
    const int brow = wgid * 128;
    const int tid = threadIdx.x, lane = tid & 63, w = tid >> 6;
    const int wr = w >> 1, wc = w & 1;
    const int r15 = lane & 15, g = lane >> 4;
    const int sw8 = r15 & 7;

    f32x4 acc[4][2];
#pragma unroll
    for (int mi = 0; mi < 4; mi++)
#pragma unroll
        for (int ni = 0; ni < 2; ni++) acc[mi][ni] = (f32x4){0.f, 0.f, 0.f, 0.f};

    auto stage_step = [&](int k0, int b) {
#pragma unroll
        for (int s = 0; s < 4; s++) {
            int slot = tid + s * 256;
            int row = slot >> 3, cc = slot & 7;
            int csrc = cc ^ (row & 7);
            int arow = brow + row; arow = arow < M ? arow : M - 1;
            g2l16(A + (size_t)arow * 768 + k0 + csrc * 4,
                  (u16*)sA[b] + ((tid & ~63) + s * 256) * 8);
        }
        {
            int row = tid >> 2, gg = tid & 3;
            int gsrc = gg ^ swz2(row);
            g2l16(Bhg + (size_t)row * 768 + k0 + gsrc * 8, sBh[b] + (tid & ~63) * 8);
        }
    };
    auto compute_step = [&](int b) {
        bf16x8 afh[4], afl[4], bfh[2];
#pragma unroll
        for (int mi = 0; mi < 4; mi++) {
            int lr = wr * 64 + mi * 16 + r15;
            f32x4 v0 = *(const f32x4*)&sA[b][lr * 32 + ((2 * g) ^ sw8) * 4];
            f32x4 v1 = *(const f32x4*)&sA[b][lr * 32 + ((2 * g + 1) ^ sw8) * 4];
            float vf[8] = {v0[0], v0[1], v0[2], v0[3], v1[0], v1[1], v1[2], v1[3]};
#pragma unroll
            for (int j = 0; j < 8; j++) {
                u16 h, l; split_tr(vf[j], h, l);
                afh[mi][j] = (short)h;
                afl[mi][j] = (short)l;
            }
        }
#pragma unroll
        for (int ni = 0; ni < 2; ni++) {
            int idx = (wc * 32 + ni * 16 + r15) * 32 + (g ^ swz2(r15)) * 8;
            bfh[ni] = *(const bf16x8*)&sBh[b][idx];
        }
#pragma unroll
        for (int mi = 0; mi < 4; mi++)
#pragma unroll
            for (int ni = 0; ni < 2; ni++)
                acc[mi][ni] = __builtin_amdgcn_mfma_f32_16x16x32_bf16(afh[mi], bfh[ni], acc[mi][ni], 0, 0, 0);
#pragma unroll
        for (int mi = 0; mi < 4; mi++)
#pragma unroll
            for (int ni = 0; ni < 2; ni++)
                acc[mi][ni] = __builtin_amdgcn_mfma_f32_16x16x32_bf16(afl[mi], bfh[ni], acc[mi][ni], 0, 0, 0);
    };

    stage_step(0, 0);
    __syncthreads();
#pragma unroll 2
    for (int t = 0; t < 23; t++) {
        stage_step((t + 1) * 32, (t + 1) & 1);
        compute_step(t & 1);
        __syncthreads();
    }
    compute_step(1);

#pragma unroll
    for (int mi = 0; mi < 4; mi++) {
#pragma unroll
        for (int ni = 0; ni < 2; ni++) {
            int col = wc * 32 + ni * 16 + r15;
            float bsv = bias[col];
            int rbase = brow + wr * 64 + mi * 16 + g * 4;
#pragma unroll
            for (int r = 0; r < 4; r++) {
                int grow = rbase + r;
                if (grow >= M) continue;
                float v = acc[mi][ni][r] + bsv;
                v = v > 0.f ? v : 0.01f * v;   // lrelu
                u16 h, l; split_tr(v, h, l);
                Ch[(size_t)grow * HD + coff + col] = h;
                Cl[(size_t)grow * HD + coff + col] = l;
            }
        }
    }
}

// ---- weight RNE-round+transpose: W f32 [K][Ncol] -> T bf16 [colOff+n][K] ----
__global__ void conv_w(const float* __restrict__ W, int K, int Ncol,
                       u16* __restrict__ Th, int colOff)
{
    int i = blockIdx.x * 256 + threadIdx.x;
    if (i >= K * Ncol) return;
    int k = i / Ncol, n = i % Ncol;
    Th[(size_t)(colOff + n) * K + k] = f2bf_rne(W[i]);
}

// ---------------- small f32 GEMM (K=5/3), bf16-pair out ----------------
template<int BM, int BN, int BK, int TM, int TN>
__global__ __launch_bounds__(256) void gemm_f32s(
    const float* __restrict__ A, int lda,
    const float* __restrict__ B, int ldb,
    const float* __restrict__ bias,
    u16* __restrict__ Ch, u16* __restrict__ Cl, int coff,
    int M, int Ncol, int K)
{
    constexpr int TX = BN / TN;
    __shared__ float As[BK][BM + 4];
    __shared__ float Bs[BK][BN + 4];
    const int tid = threadIdx.x;
    const int tx = tid % TX, ty = tid / TX;
    const int brow = blockIdx.y * BM;
    const int bcol = blockIdx.x * BN;
    float acc[TM][TN];
#pragma unroll
    for (int i = 0; i < TM; i++)
#pragma unroll
        for (int j = 0; j < TN; j++) acc[i][j] = 0.f;
    for (int k0 = 0; k0 < K; k0 += BK) {
#pragma unroll
        for (int idx = tid; idx < BM * BK; idx += 256) {
            int m = idx / BK, k = idx % BK;
            int gr = brow + m, gk = k0 + k;
            As[k][m] = (gr < M && gk < K) ? A[(size_t)gr * lda + gk] : 0.f;
        }
#pragma unroll
        for (int idx = tid; idx < BK * BN; idx += 256) {
            int k = idx / BN, n = idx % BN;
            int gk = k0 + k, gc = bcol + n;
            Bs[k][n] = (gk < K && gc < Ncol) ? B[(size_t)gk * ldb + gc] : 0.f;
        }
        __syncthreads();
#pragma unroll
        for (int k = 0; k < BK; k++) {
            float a[TM], b[TN];
#pragma unroll
            for (int i = 0; i < TM; i++) a[i] = As[k][ty * TM + i];
#pragma unroll
            for (int j = 0; j < TN; j++) b[j] = Bs[k][tx * TN + j];
#pragma unroll
            for (int i = 0; i < TM; i++)
#pragma unroll
                for (int j = 0; j < TN; j++) acc[i][j] = fmaf(a[i], b[j], acc[i][j]);
        }
        __syncthreads();
    }
#pragma unroll
    for (int i = 0; i < TM; i++) {
        int gr = brow + ty * TM + i;
        if (gr >= M) continue;
#pragma unroll
        for (int j = 0; j < TN; j++) {
            int gc = bcol + tx * TN + j;
            if (gc >= Ncol) continue;
            float v = acc[i][j] + bias[gc];
            v = v > 0.f ? v : 0.01f * v;
            u16 h, l; split_tr(v, h, l);
            Ch[(size_t)gr * HD + coff + gc] = h;
            Cl[(size_t)gr * HD + coff + gc] = l;
        }
    }
}

// ---------------- CSR build ----------------
__global__ void count_seg(const int* __restrict__ ei, const int* __restrict__ et,
                          int* __restrict__ segc)
{
    int e = blockIdx.x * blockDim.x + threadIdx.x;
    if (e < EE) {
        int dst = ei[EE + e];
        int r = et[e];
        atomicAdd(&segc[r * NN + dst], 1);
    }
}

__global__ __launch_bounds__(256) void scan_local(const int* __restrict__ segc,
                                                  int* __restrict__ offs,
                                                  int* __restrict__ bsum)
{
    int b = blockIdx.x;
    int base = b * CHUNK;
    int tid = threadIdx.x;
    int lane = tid & 63, wave = tid >> 6;
    __shared__ int wsum[4];
    int vals[8];
    int i0 = base + tid * 8;
    int s = 0;
    if (i0 + 7 < NSEG) {
        int4 v0 = *(const int4*)&segc[i0];
        int4 v1 = *(const int4*)&segc[i0 + 4];
        vals[0] = v0.x; vals[1] = v0.y; vals[2] = v0.z; vals[3] = v0.w;
        vals[4] = v1.x; vals[5] = v1.y; vals[6] = v1.z; vals[7] = v1.w;
    } else {
#pragma unroll
        for (int j = 0; j < 8; j++) vals[j] = (i0 + j < NSEG) ? segc[i0 + j] : 0;
    }
#pragma unroll
    for (int j = 0; j < 8; j++) s += vals[j];
    int v = s;
#pragma unroll
    for (int off = 1; off < 64; off <<= 1) {
        int u = __shfl_up(v, off);
        if (lane >= off) v += u;
    }
    if (lane == 63) wsum[wave] = v;
    __syncthreads();
    int wbase = 0;
#pragma unroll
    for (int ww = 0; ww < 4; ww++) if (ww < wave) wbase += wsum[ww];
    int run = wbase + v - s;
#pragma unroll
    for (int j = 0; j < 8; j++) {
        run += vals[j];
        int i = i0 + j;
        if (i < NSEG) offs[i + 1] = run;
    }
    if (tid == 0) {
        int t = 0;
#pragma unroll
        for (int ww = 0; ww < 4; ww++) t += wsum[ww];
        bsum[b] = t;
    }
}

__global__ void scan_bsum(const int* __restrict__ bsum, int* __restrict__ bbase)
{
    int lane = threadIdx.x;
    int c = (lane < NB) ? bsum[lane] : 0;
    int v = c;
#pragma unroll
    for (int off = 1; off < 64; off <<= 1) {
        int u = __shfl_up(v, off);
        if (lane >= off) v += u;
    }
    if (lane < NB) bbase[lane] = v - c;
}

__global__ void add_base(int* __restrict__ offs, const int* __restrict__ bbase)
{
    int i = blockIdx.x * blockDim.x + threadIdx.x;
    if (i < NSEG) offs[i + 1] += bbase[i / CHUNK];
    if (i == 0) offs[0] = 0;
}

__global__ void fill_src(const int* __restrict__ ei, const int* __restrict__ et,
                         const int* __restrict__ offs, int* __restrict__ cursor,
                         int* __restrict__ src_list)
{
    int e = blockIdx.x * blockDim.x + threadIdx.x;
    if (e < EE) {
        int src = ei[e];
        int dst = ei[EE + e];
        int s = et[e] * NN + dst;
        int pos = offs[s] + atomicAdd(&cursor[s], 1);
        src_list[pos] = src;
    }
}

// ---------------- gather: v = base + sum_r mean(hrel_bf16) ----------------
template<int OUTM>
__global__ __launch_bounds__(256) void gather_mean_b(
    const u16* __restrict__ hrelb,
    const int* __restrict__ offs,
    const int* __restrict__ src_list,
    const float* __restrict__ basein,
    u16* __restrict__ Oh, u16* __restrict__ Ol,
    float* __restrict__ Of)
{
    int d = blockIdx.x * 4 + (threadIdx.x >> 6);
    if (d >= NN) return;
    int lane = threadIdx.x & 63;
    f32x4 acc = {0.f, 0.f, 0.f, 0.f};
#pragma unroll
    for (int r = 0; r < 2; r++) {
        int s = r * NN + d;
        int start = offs[s], end = offs[s + 1];
        if (start == end) continue;
        f32x4 a = {0.f, 0.f, 0.f, 0.f};
        const u16* hb = hrelb + (size_t)r * NN * HD;
        for (int i = start; i < end; i++) {
            int src = src_list[i];
            uint2 wv = *(const uint2*)(hb + (size_t)src * HD + lane * 4);
            a.x += __uint_as_float(wv.x << 16);
            a.y += __uint_as_float(wv.x & 0xFFFF0000u);
            a.z += __uint_as_float(wv.y << 16);
            a.w += __uint_as_float(wv.y & 0xFFFF0000u);
        }
        float inv = 1.0f / (float)(end - start);
        acc.x += a.x * inv; acc.y += a.y * inv;
        acc.z += a.z * inv; acc.w += a.w * inv;
    }
    float4 b = ((const float4*)(basein + (size_t)d * HD))[lane];
    float v0 = b.x + acc.x, v1 = b.y + acc.y, v2 = b.z + acc.z, v3 = b.w + acc.w;
    if (OUTM == 0) {
        u16 h0, l0, h1, l1, h2, l2, h3, l3;
        split_tr(v0, h0, l0); split_tr(v1, h1, l1);
        split_tr(v2, h2, l2); split_tr(v3, h3, l3);
        uint2 uh, ul;
        uh.x = (unsigned)h0 | ((unsigned)h1 << 16);
        uh.y = (unsigned)h2 | ((unsigned)h3 << 16);
        ul.x = (unsigned)l0 | ((unsigned)l1 << 16);
        ul.y = (unsigned)l2 | ((unsigned)l3 << 16);
        *(uint2*)(Oh + (size_t)d * HD + lane * 4) = uh;
        *(uint2*)(Ol + (size_t)d * HD + lane * 4) = ul;
    } else {
        float4 o = {v0, v1, v2, v3};
        ((float4*)(Of + (size_t)d * HD))[lane] = o;
    }
}

// ---------------- output head ----------------
__global__ __launch_bounds__(256) void out_proj(
    const float* __restrict__ x, const float* __restrict__ w,
    const float* __restrict__ b, float* __restrict__ out)
{
    int n = blockIdx.x * 4 + (threadIdx.x >> 6);
    if (n >= NN) return;
    int lane = threadIdx.x & 63;
    const float4* xr4 = (const float4*)(x + (size_t)n * HD);
    float4 v = xr4[lane];
    int k = lane * 4;
    float a0 = v.x * w[(k + 0) * 2 + 0] + v.y * w[(k + 1) * 2 + 0]
             + v.z * w[(k + 2) * 2 + 0] + v.w * w[(k + 3) * 2 + 0];
    float a1 = v.x * w[(k + 0) * 2 + 1] + v.y * w[(k + 1) * 2 + 1]
             + v.z * w[(k + 2) * 2 + 1] + v.w * w[(k + 3) * 2 + 1];
#pragma unroll
    for (int off = 32; off > 0; off >>= 1) {
        a0 += __shfl_down(a0, off);
        a1 += __shfl_down(a1, off);
    }
    if (lane == 0) {
        out[(size_t)n * 2 + 0] = a0 + b[0];
        out[(size_t)n * 2 + 1] = a1 + b[1];
    }
}

extern "C" void kernel_launch(void* const* d_in, const int* in_sizes, int n_in,
                              void* d_out, int out_size, void* d_ws, size_t ws_size,
                              hipStream_t stream)
{
    const float* des   = (const float*)d_in[0];
    const float* tweet = (const float*)d_in[1];
    const float* nump  = (const float*)d_in[2];
    const float* catp  = (const float*)d_in[3];
    const int*   ei    = (const int*)d_in[4];
    const int*   et    = (const int*)d_in[5];
    const float* w_des = (const float*)d_in[6],  *b_des = (const float*)d_in[7];
    const float* w_tw  = (const float*)d_in[8],  *b_tw  = (const float*)d_in[9];
    const float* w_num = (const float*)d_in[10], *b_num = (const float*)d_in[11];
    const float* w_cat = (const float*)d_in[12], *b_cat = (const float*)d_in[13];
    const float* w_in  = (const float*)d_in[14], *b_in  = (const float*)d_in[15];
    const float* weight1 = (const float*)d_in[16], *root1 = (const float*)d_in[17], *bias1 = (const float*)d_in[18];
    const float* weight2 = (const float*)d_in[19], *root2 = (const float*)d_in[20], *bias2 = (const float*)d_in[21];
    const float* w_out = (const float*)d_in[22], *b_out = (const float*)d_in[23];
    float* outp = (float*)d_out;

    const int HSZ = HD * HD, PSZ = 768 * 64;

    // ---- workspace carve-up ----
    float* base  = (float*)d_ws;                       // [N,HD] f32
    u16*   hrelb = (u16*)(base + (size_t)NN * HD);     // [2,N,HD] bf16
    u16*   xh    = hrelb + (size_t)2 * NN * HD;
    u16*   xl    = xh + (size_t)NN * HD;
    u16*   yh    = xl + (size_t)NN * HD;
    u16*   yl    = yh + (size_t)NN * HD;
    int*   offs  = (int*)(yl + (size_t)NN * HD);
    int*   segc  = offs + (NSEG + 1);
    int*   srcl  = segc + NSEG;
    int*   bsum  = srcl + EE;
    int*   bbase = bsum + NB;
    uintptr_t wp = ((uintptr_t)(bbase + NB) + 15) & ~(uintptr_t)15;
    u16* desB = (u16*)wp;
    u16* twB  = desB + PSZ;
    u16* winB = twB + PSZ;
    u16* cat1 = winB + HSZ;
    u16* cat2 = cat1 + 3 * HSZ;

    // ---- CSR build ----
    hipMemsetAsync(segc, 0, NSEG * sizeof(int), stream);
    count_seg<<<(EE + 255) / 256, 256, 0, stream>>>(ei, et, segc);
    scan_local<<<NB, 256, 0, stream>>>(segc, offs, bsum);
    scan_bsum<<<1, 64, 0, stream>>>(bsum, bbase);
    add_base<<<(NSEG + 255) / 256, 256, 0, stream>>>(offs, bbase);
    hipMemsetAsync(segc, 0, NSEG * sizeof(int), stream);
    fill_src<<<(EE + 255) / 256, 256, 0, stream>>>(ei, et, offs, segc, srcl);

    // ---- weight RNE+transpose ----
    conv_w<<<(PSZ + 255) / 256, 256, 0, stream>>>(w_des, 768, 64, desB, 0);
    conv_w<<<(PSZ + 255) / 256, 256, 0, stream>>>(w_tw,  768, 64, twB,  0);
    conv_w<<<(HSZ + 255) / 256, 256, 0, stream>>>(w_in, HD, HD, winB, 0);
    conv_w<<<(HSZ + 255) / 256, 256, 0, stream>>>(weight1,       HD, HD, cat1, 0);
    conv_w<<<(HSZ + 255) / 256, 256, 0, stream>>>(weight1 + HSZ, HD, HD, cat1, 256);
    conv_w<<<(HSZ + 255) / 256, 256, 0, stream>>>(root1,         HD, HD, cat1, 512);
    conv_w<<<(HSZ + 255) / 256, 256, 0, stream>>>(weight2,       HD, HD, cat2, 0);
    conv_w<<<(HSZ + 255) / 256, 256, 0, stream>>>(weight2 + HSZ, HD, HD, cat2, 256);
    conv_w<<<(HSZ + 255) / 256, 256, 0, stream>>>(root2,         HD, HD, cat2, 512);

    const int NYB = (NN + 127) / 128;   // 391 row blocks

    // ---- feature projections -> xh/xl ----
    gemm_f32L<<<NYB, 256, 0, stream>>>(des,   desB, b_des, xh, xl, 0,  NN);
    gemm_f32L<<<NYB, 256, 0, stream>>>(tweet, twB,  b_tw,  xh, xl, 64, NN);
    dim3 gsmall(1, (NN + 63) / 64);
    gemm_f32s<64, 64, 8, 4, 4><<<gsmall, 256, 0, stream>>>(nump, 5, w_num, 64, b_num, xh, xl, 128, NN, 64, 5);
    gemm_f32s<64, 64, 8, 4, 4><<<gsmall, 256, 0, stream>>>(catp, 3, w_cat, 64, b_cat, xh, xl, 192, NN, 64, 3);

    // ---- y = lrelu(x @ w_in + b_in) -> yh/yl ----
    gemm_bf16L<1><<<2 * NYB, 256, 0, stream>>>(xh, xl, winB, b_in, yh, yl, nullptr, NN, 2);

    // ---- layer 1: fused [W_r0|W_r1|root1] -> hrelb (bf16) + base (f32) ----
    gemm_bf16L<2><<<6 * NYB, 256, 0, stream>>>(yh, yl, cat1, bias1, hrelb, nullptr, base, NN, 6);
    gather_mean_b<0><<<(NN + 3) / 4, 256, 0, stream>>>(hrelb, offs, srcl, base, xh, xl, nullptr);

    // ---- layer 2 ----
    gemm_bf16L<2><<<6 * NYB, 256, 0, stream>>>(xh, xl, cat2, bias2, hrelb, nullptr, base, NN, 6);
    gather_mean_b<1><<<(NN + 3) / 4, 256, 0, stream>>>(hrelb, offs, srcl, base, nullptr, nullptr, base);

    // ---- logits ----
    out_proj<<<(NN + 3) / 4, 256, 0, stream>>>(base, w_out, b_out, outp);
}

// Round 9
// 619.155 us; speedup vs baseline: 1.1719x; 1.1719x over previous
//
#include <hip/hip_runtime.h>

#define NN 50000
#define EE 800000
#define HD 256
#define NSEG (2 * NN)
#define CHUNK 2048
#define NB ((NSEG + CHUNK - 1) / CHUNK)

typedef unsigned short u16;
typedef short bf16x8 __attribute__((ext_vector_type(8)));
typedef float f32x4 __attribute__((ext_vector_type(4)));

__device__ __forceinline__ u16 f2bf_rne(float f) {
    unsigned u = __float_as_uint(f);
    return (u16)((u + 0x7FFF + ((u >> 16) & 1)) >> 16);
}
// trunc hi + RNE residual: (h,l) represents v to ~2^-17 relative
__device__ __forceinline__ void split_tr(float v, u16& h, u16& l) {
    unsigned u = __float_as_uint(v);
    h = (u16)(u >> 16);
    l = f2bf_rne(v - __uint_as_float(u & 0xFFFF0000u));
}

// bijective XCD-chunked swizzle (m204)
__device__ __forceinline__ int xcd_swizzle(int orig, int nwg) {
    int q = nwg >> 3, r = nwg & 7;
    int xcd = orig & 7, idx = orig >> 3;
    return (xcd < r ? xcd * (q + 1) : r * (q + 1) + (xcd - r) * q) + idx;
}

// async global->LDS, 16B per lane; LDS dest = wave-uniform base + lane*16
__device__ __forceinline__ void g2l16(const void* g, void* l) {
    __builtin_amdgcn_global_load_lds(
        (const __attribute__((address_space(1))) void*)g,
        (__attribute__((address_space(3))) void*)l, 16, 0, 0);
}

// bank swizzle for 64B-row bf16 tiles
__device__ __forceinline__ int swz2(int row) { return (row & 2) | ((row >> 2) & 1); }

// stage one 128x32 bf16 tile from G[rc][K] (k-contiguous), source-swizzled
__device__ __forceinline__ void stage_bf16(const u16* __restrict__ G, u16* S,
                                           int base_rc, int maxrc, int K, int k0, int tid) {
#pragma unroll
    for (int s = 0; s < 2; s++) {
        int slot = tid + s * 256;
        int row = slot >> 2, gg = slot & 3;
        int gsrc = gg ^ swz2(row);
        int arow = base_rc + row; arow = arow < maxrc ? arow : maxrc - 1;
        g2l16(G + (size_t)arow * K + k0 + gsrc * 8, S + ((tid & ~63) + s * 256) * 8);
    }
}

// ============ double-buffered bf16 GEMM: A hi/lo pair [M][256], B bf16 [Ncol][256] ====
// acc = Ah*Bh + Al*Bh (weights RNE bf16; activation pair exact).
// BM=BN=128, 4 waves 2x2, MFMA 16x16x32, k-map k=k0+g*8+j for both operands.
// MODE 1: lrelu -> bf16 pair out (w_in). MODE 2: relu; col<512 -> bf16 hrel; else f32 O2.
template<int MODE>
__global__ __launch_bounds__(256) void gemm_bf16L(
    const u16* __restrict__ Ahg, const u16* __restrict__ Alg,
    const u16* __restrict__ Bhg,
    const float* __restrict__ bias,
    u16* __restrict__ O1h, u16* __restrict__ O1l, float* __restrict__ O2,
    int M, int nxb)
{
    __shared__ __align__(16) u16 sAh[2][128 * 32];
    __shared__ __align__(16) u16 sAl[2][128 * 32];
    __shared__ __align__(16) u16 sBh[2][128 * 32];
    const int wgid = xcd_swizzle(blockIdx.x, gridDim.x);
    const int brow = (wgid / nxb) * 128, bcol = (wgid % nxb) * 128;
    const int tid = threadIdx.x, lane = tid & 63, w = tid >> 6;
    const int wr = w >> 1, wc = w & 1;
    const int r15 = lane & 15, g = lane >> 4;
    const int fsw = (g ^ swz2(r15)) * 8;

    f32x4 acc[4][4];
#pragma unroll
    for (int mi = 0; mi < 4; mi++)
#pragma unroll
        for (int ni = 0; ni < 4; ni++) acc[mi][ni] = (f32x4){0.f, 0.f, 0.f, 0.f};

    auto stage_step = [&](int k0, int b) {
        stage_bf16(Ahg, sAh[b], brow, M, 256, k0, tid);
        stage_bf16(Alg, sAl[b], brow, M, 256, k0, tid);
        stage_bf16(Bhg, sBh[b], bcol, 1 << 30, 256, k0, tid);
    };
    auto compute_step = [&](int b) {
        bf16x8 afh[4], afl[4], bfh[4];
#pragma unroll
        for (int mi = 0; mi < 4; mi++) {
            int idx = (wr * 64 + mi * 16 + r15) * 32 + fsw;
            afh[mi] = *(const bf16x8*)&sAh[b][idx];
            afl[mi] = *(const bf16x8*)&sAl[b][idx];
        }
#pragma unroll
        for (int ni = 0; ni < 4; ni++) {
            int idx = (wc * 64 + ni * 16 + r15) * 32 + fsw;
            bfh[ni] = *(const bf16x8*)&sBh[b][idx];
        }
#pragma unroll
        for (int mi = 0; mi < 4; mi++)
#pragma unroll
            for (int ni = 0; ni < 4; ni++)
                acc[mi][ni] = __builtin_amdgcn_mfma_f32_16x16x32_bf16(afh[mi], bfh[ni], acc[mi][ni], 0, 0, 0);
#pragma unroll
        for (int mi = 0; mi < 4; mi++)
#pragma unroll
            for (int ni = 0; ni < 4; ni++)
                acc[mi][ni] = __builtin_amdgcn_mfma_f32_16x16x32_bf16(afl[mi], bfh[ni], acc[mi][ni], 0, 0, 0);
    };

    stage_step(0, 0);
    __syncthreads();
#pragma unroll 2
    for (int t = 0; t < 7; t++) {
        stage_step((t + 1) * 32, (t + 1) & 1);
        compute_step(t & 1);
        __syncthreads();
    }
    compute_step(1);

#pragma unroll
    for (int mi = 0; mi < 4; mi++) {
#pragma unroll
        for (int ni = 0; ni < 4; ni++) {
            int col = bcol + wc * 64 + ni * 16 + r15;
            float bsv = bias[col & (HD - 1)];
            int rbase = brow + wr * 64 + mi * 16 + g * 4;
#pragma unroll
            for (int r = 0; r < 4; r++) {
                int grow = rbase + r;
                if (grow >= M) continue;
                float v = acc[mi][ni][r] + bsv;
                if (MODE == 1) {
                    v = v > 0.f ? v : 0.01f * v;   // lrelu
                    u16 h, l; split_tr(v, h, l);
                    O1h[(size_t)grow * HD + col] = h;
                    O1l[(size_t)grow * HD + col] = l;
                } else {
                    v = fmaxf(v, 0.f);             // relu
                    if (col < 2 * HD) {
                        O1h[((size_t)(col >> 8) * NN + grow) * HD + (col & (HD - 1))] = f2bf_rne(v);
                    } else {
                        O2[(size_t)grow * HD + (col & (HD - 1))] = v;
                    }
                }
            }
        }
    }
}

// ============ fused dual-projection GEMM (des & tweet, K=768) ============
// p = blockIdx&1 selects projection. BM=64, BN=64, 4 waves 2x2 (MI=NI=2).
// A f32 staged raw, split hi/lo in-register. B bf16 [64][768]. lrelu, bf16-pair out.
__global__ __launch_bounds__(256) void gemm_projP(
    const float* __restrict__ A0, const float* __restrict__ A1,
    const u16* __restrict__ B0, const u16* __restrict__ B1,
    const float* __restrict__ bias0, const float* __restrict__ bias1,
    u16* __restrict__ Ch, u16* __restrict__ Cl)
{
    __shared__ __align__(16) float sA[2][64 * 32];
    __shared__ __align__(16) u16 sB[2][64 * 32];
    const int p = blockIdx.x & 1;
    const int brow = (blockIdx.x >> 1) * 64;
    const float* __restrict__ A = p ? A1 : A0;
    const u16* __restrict__ B = p ? B1 : B0;
    const float* __restrict__ bias = p ? bias1 : bias0;
    const int coff = p * 64;

    const int tid = threadIdx.x, lane = tid & 63, w = tid >> 6;
    const int wr = w >> 1, wc = w & 1;
    const int r15 = lane & 15, g = lane >> 4;
    const int sw8 = r15 & 7;

    f32x4 acc[2][2];
#pragma unroll
    for (int mi = 0; mi < 2; mi++)
#pragma unroll
        for (int ni = 0; ni < 2; ni++) acc[mi][ni] = (f32x4){0.f, 0.f, 0.f, 0.f};

    auto stage_step = [&](int k0, int b) {
#pragma unroll
        for (int s = 0; s < 2; s++) {
            int slot = tid + s * 256;
            int row = slot >> 3, cc = slot & 7;
            int csrc = cc ^ (row & 7);
            int arow = brow + row; arow = arow < NN ? arow : NN - 1;
            g2l16(A + (size_t)arow * 768 + k0 + csrc * 4,
                  (u16*)sA[b] + ((tid & ~63) + s * 256) * 8);
        }
        {
            int row = tid >> 2, gg = tid & 3;
            int gsrc = gg ^ swz2(row);
            g2l16(B + (size_t)row * 768 + k0 + gsrc * 8, sB[b] + (tid & ~63) * 8);
        }
    };
    auto compute_step = [&](int b) {
        bf16x8 afh[2], afl[2], bfh[2];
#pragma unroll
        for (int mi = 0; mi < 2; mi++) {
            int lr = wr * 32 + mi * 16 + r15;
            f32x4 v0 = *(const f32x4*)&sA[b][lr * 32 + ((2 * g) ^ sw8) * 4];
            f32x4 v1 = *(const f32x4*)&sA[b][lr * 32 + ((2 * g + 1) ^ sw8) * 4];
            float vf[8] = {v0[0], v0[1], v0[2], v0[3], v1[0], v1[1], v1[2], v1[3]};
#pragma unroll
            for (int j = 0; j < 8; j++) {
                u16 h, l; split_tr(vf[j], h, l);
                afh[mi][j] = (short)h;
                afl[mi][j] = (short)l;
            }
        }
#pragma unroll
        for (int ni = 0; ni < 2; ni++) {
            int idx = (wc * 32 + ni * 16 + r15) * 32 + (g ^ swz2(r15)) * 8;
            bfh[ni] = *(const bf16x8*)&sB[b][idx];
        }
#pragma unroll
        for (int mi = 0; mi < 2; mi++)
#pragma unroll
            for (int ni = 0; ni < 2; ni++)
                acc[mi][ni] = __builtin_amdgcn_mfma_f32_16x16x32_bf16(afh[mi], bfh[ni], acc[mi][ni], 0, 0, 0);
#pragma unroll
        for (int mi = 0; mi < 2; mi++)
#pragma unroll
            for (int ni = 0; ni < 2; ni++)
                acc[mi][ni] = __builtin_amdgcn_mfma_f32_16x16x32_bf16(afl[mi], bfh[ni], acc[mi][ni], 0, 0, 0);
    };

    stage_step(0, 0);
    __syncthreads();
#pragma unroll 2
    for (int t = 0; t < 23; t++) {
        stage_step((t + 1) * 32, (t + 1) & 1);
        compute_step(t & 1);
        __syncthreads();
    }
    compute_step(1);

#pragma unroll
    for (int mi = 0; mi < 2; mi++) {
#pragma unroll
        for (int ni = 0; ni < 2; ni++) {
            int col = wc * 32 + ni * 16 + r15;
            float bsv = bias[col];
            int rbase = brow + wr * 32 + mi * 16 + g * 4;
#pragma unroll
            for (int r = 0; r < 4; r++) {
                int grow = rbase + r;
                if (grow >= NN) continue;
                float v = acc[mi][ni][r] + bsv;
                v = v > 0.f ? v : 0.01f * v;   // lrelu
                u16 h, l; split_tr(v, h, l);
                Ch[(size_t)grow * HD + coff + col] = h;
                Cl[(size_t)grow * HD + coff + col] = l;
            }
        }
    }
}

// ---- weight RNE-round+transpose: W f32 [K][Ncol] -> T bf16 [colOff+n][K] ----
__global__ void conv_w(const float* __restrict__ W, int K, int Ncol,
                       u16* __restrict__ Th, int colOff)
{
    int i = blockIdx.x * 256 + threadIdx.x;
    if (i >= K * Ncol) return;
    int k = i / Ncol, n = i % Ncol;
    Th[(size_t)(colOff + n) * K + k] = f2bf_rne(W[i]);
}

// ---------------- small f32 GEMM (K=5/3), bf16-pair out ----------------
template<int BM, int BN, int BK, int TM, int TN>
__global__ __launch_bounds__(256) void gemm_f32s(
    const float* __restrict__ A, int lda,
    const float* __restrict__ B, int ldb,
    const float* __restrict__ bias,
    u16* __restrict__ Ch, u16* __restrict__ Cl, int coff,
    int M, int Ncol, int K)
{
    constexpr int TX = BN / TN;
    __shared__ float As[BK][BM + 4];
    __shared__ float Bs[BK][BN + 4];
    const int tid = threadIdx.x;
    const int tx = tid % TX, ty = tid / TX;
    const int brow = blockIdx.y * BM;
    const int bcol = blockIdx.x * BN;
    float acc[TM][TN];
#pragma unroll
    for (int i = 0; i < TM; i++)
#pragma unroll
        for (int j = 0; j < TN; j++) acc[i][j] = 0.f;
    for (int k0 = 0; k0 < K; k0 += BK) {
#pragma unroll
        for (int idx = tid; idx < BM * BK; idx += 256) {
            int m = idx / BK, k = idx % BK;
            int gr = brow + m, gk = k0 + k;
            As[k][m] = (gr < M && gk < K) ? A[(size_t)gr * lda + gk] : 0.f;
        }
#pragma unroll
        for (int idx = tid; idx < BK * BN; idx += 256) {
            int k = idx / BN, n = idx % BN;
            int gk = k0 + k, gc = bcol + n;
            Bs[k][n] = (gk < K && gc < Ncol) ? B[(size_t)gk * ldb + gc] : 0.f;
        }
        __syncthreads();
#pragma unroll
        for (int k = 0; k < BK; k++) {
            float a[TM], b[TN];
#pragma unroll
            for (int i = 0; i < TM; i++) a[i] = As[k][ty * TM + i];
#pragma unroll
            for (int j = 0; j < TN; j++) b[j] = Bs[k][tx * TN + j];
#pragma unroll
            for (int i = 0; i < TM; i++)
#pragma unroll
                for (int j = 0; j < TN; j++) acc[i][j] = fmaf(a[i], b[j], acc[i][j]);
        }
        __syncthreads();
    }
#pragma unroll
    for (int i = 0; i < TM; i++) {
        int gr = brow + ty * TM + i;
        if (gr >= M) continue;
#pragma unroll
        for (int j = 0; j < TN; j++) {
            int gc = bcol + tx * TN + j;
            if (gc >= Ncol) continue;
            float v = acc[i][j] + bias[gc];
            v = v > 0.f ? v : 0.01f * v;
            u16 h, l; split_tr(v, h, l);
            Ch[(size_t)gr * HD + coff + gc] = h;
            Cl[(size_t)gr * HD + coff + gc] = l;
        }
    }
}

// ---------------- CSR build ----------------
__global__ void count_seg(const int* __restrict__ ei, const int* __restrict__ et,
                          int* __restrict__ segc)
{
    int e = blockIdx.x * blockDim.x + threadIdx.x;
    if (e < EE) {
        int dst = ei[EE + e];
        int r = et[e];
        atomicAdd(&segc[r * NN + dst], 1);
    }
}

__global__ __launch_bounds__(256) void scan_local(const int* __restrict__ segc,
                                                  int* __restrict__ offs,
                                                  int* __restrict__ bsum)
{
    int b = blockIdx.x;
    int base = b * CHUNK;
    int tid = threadIdx.x;
    int lane = tid & 63, wave = tid >> 6;
    __shared__ int wsum[4];
    int vals[8];
    int i0 = base + tid * 8;
    int s = 0;
    if (i0 + 7 < NSEG) {
        int4 v0 = *(const int4*)&segc[i0];
        int4 v1 = *(const int4*)&segc[i0 + 4];
        vals[0] = v0.x; vals[1] = v0.y; vals[2] = v0.z; vals[3] = v0.w;
        vals[4] = v1.x; vals[5] = v1.y; vals[6] = v1.z; vals[7] = v1.w;
    } else {
#pragma unroll
        for (int j = 0; j < 8; j++) vals[j] = (i0 + j < NSEG) ? segc[i0 + j] : 0;
    }
#pragma unroll
    for (int j = 0; j < 8; j++) s += vals[j];
    int v = s;
#pragma unroll
    for (int off = 1; off < 64; off <<= 1) {
        int u = __shfl_up(v, off);
        if (lane >= off) v += u;
    }
    if (lane == 63) wsum[wave] = v;
    __syncthreads();
    int wbase = 0;
#pragma unroll
    for (int ww = 0; ww < 4; ww++) if (ww < wave) wbase += wsum[ww];
    int run = wbase + v - s;
#pragma unroll
    for (int j = 0; j < 8; j++) {
        run += vals[j];
        int i = i0 + j;
        if (i < NSEG) offs[i + 1] = run;
    }
    if (tid == 0) {
        int t = 0;
#pragma unroll
        for (int ww = 0; ww < 4; ww++) t += wsum[ww];
        bsum[b] = t;
    }
}

__global__ void scan_bsum(const int* __restrict__ bsum, int* __restrict__ bbase)
{
    int lane = threadIdx.x;
    int c = (lane < NB) ? bsum[lane] : 0;
    int v = c;
#pragma unroll
    for (int off = 1; off < 64; off <<= 1) {
        int u = __shfl_up(v, off);
        if (lane >= off) v += u;
    }
    if (lane < NB) bbase[lane] = v - c;
}

__global__ void add_base(int* __restrict__ offs, const int* __restrict__ bbase)
{
    int i = blockIdx.x * blockDim.x + threadIdx.x;
    if (i < NSEG) offs[i + 1] += bbase[i / CHUNK];
    if (i == 0) offs[0] = 0;
}

__global__ void fill_src(const int* __restrict__ ei, const int* __restrict__ et,
                         const int* __restrict__ offs, int* __restrict__ cursor,
                         int* __restrict__ src_list)
{
    int e = blockIdx.x * blockDim.x + threadIdx.x;
    if (e < EE) {
        int src = ei[e];
        int dst = ei[EE + e];
        int s = et[e] * NN + dst;
        int pos = offs[s] + atomicAdd(&cursor[s], 1);
        src_list[pos] = src;
    }
}

// ---------------- gather: v = base + sum_r mean(hrel_bf16) ----------------
// OUTM 0: write bf16 hi/lo pair (next layer input).
// OUTM 1: fused head: logits[d,c] = v . w_out[:,c] + b_out[c]
template<int OUTM>
__global__ __launch_bounds__(256) void gather_mean_b(
    const u16* __restrict__ hrelb,
    const int* __restrict__ offs,
    const int* __restrict__ src_list,
    const float* __restrict__ basein,
    u16* __restrict__ Oh, u16* __restrict__ Ol,
    const float* __restrict__ wout, const float* __restrict__ bout,
    float* __restrict__ logits)
{
    int d = blockIdx.x * 4 + (threadIdx.x >> 6);
    if (d >= NN) return;
    int lane = threadIdx.x & 63;
    f32x4 acc = {0.f, 0.f, 0.f, 0.f};
#pragma unroll
    for (int r = 0; r < 2; r++) {
        int s = r * NN + d;
        int start = offs[s], end = offs[s + 1];
        if (start == end) continue;
        f32x4 a = {0.f, 0.f, 0.f, 0.f};
        const u16* hb = hrelb + (size_t)r * NN * HD;
        for (int i = start; i < end; i++) {
            int src = src_list[i];
            uint2 wv = *(const uint2*)(hb + (size_t)src * HD + lane * 4);
            a.x += __uint_as_float(wv.x << 16);
            a.y += __uint_as_float(wv.x & 0xFFFF0000u);
            a.z += __uint_as_float(wv.y << 16);
            a.w += __uint_as_float(wv.y & 0xFFFF0000u);
        }
        float inv = 1.0f / (float)(end - start);
        acc.x += a.x * inv; acc.y += a.y * inv;
        acc.z += a.z * inv; acc.w += a.w * inv;
    }
    float4 b = ((const float4*)(basein + (size_t)d * HD))[lane];
    float v0 = b.x + acc.x, v1 = b.y + acc.y, v2 = b.z + acc.z, v3 = b.w + acc.w;
    if (OUTM == 0) {
        u16 h0, l0, h1, l1, h2, l2, h3, l3;
        split_tr(v0, h0, l0); split_tr(v1, h1, l1);
        split_tr(v2, h2, l2); split_tr(v3, h3, l3);
        uint2 uh, ul;
        uh.x = (unsigned)h0 | ((unsigned)h1 << 16);
        uh.y = (unsigned)h2 | ((unsigned)h3 << 16);
        ul.x = (unsigned)l0 | ((unsigned)l1 << 16);
        ul.y = (unsigned)l2 | ((unsigned)l3 << 16);
        *(uint2*)(Oh + (size_t)d * HD + lane * 4) = uh;
        *(uint2*)(Ol + (size_t)d * HD + lane * 4) = ul;
    } else {
        int k = lane * 4;
        float a0 = v0 * wout[(k + 0) * 2 + 0] + v1 * wout[(k + 1) * 2 + 0]
                 + v2 * wout[(k + 2) * 2 + 0] + v3 * wout[(k + 3) * 2 + 0];
        float a1 = v0 * wout[(k + 0) * 2 + 1] + v1 * wout[(k + 1) * 2 + 1]
                 + v2 * wout[(k + 2) * 2 + 1] + v3 * wout[(k + 3) * 2 + 1];
#pragma unroll
        for (int off = 32; off > 0; off >>= 1) {
            a0 += __shfl_down(a0, off);
            a1 += __shfl_down(a1, off);
        }
        if (lane == 0) {
            logits[(size_t)d * 2 + 0] = a0 + bout[0];
            logits[(size_t)d * 2 + 1] = a1 + bout[1];
        }
    }
}

extern "C" void kernel_launch(void* const* d_in, const int* in_sizes, int n_in,
                              void* d_out, int out_size, void* d_ws, size_t ws_size,
                              hipStream_t stream)
{
    const float* des   = (const float*)d_in[0];
    const float* tweet = (const float*)d_in[1];
    const float* nump  = (const float*)d_in[2];
    const float* catp  = (const float*)d_in[3];
    const int*   ei    = (const int*)d_in[4];
    const int*   et    = (const int*)d_in[5];
    const float* w_des = (const float*)d_in[6],  *b_des = (const float*)d_in[7];
    const float* w_tw  = (const float*)d_in[8],  *b_tw  = (const float*)d_in[9];
    const float* w_num = (const float*)d_in[10], *b_num = (const float*)d_in[11];
    const float* w_cat = (const float*)d_in[12], *b_cat = (const float*)d_in[13];
    const float* w_in  = (const float*)d_in[14], *b_in  = (const float*)d_in[15];
    const float* weight1 = (const float*)d_in[16], *root1 = (const float*)d_in[17], *bias1 = (const float*)d_in[18];
    const float* weight2 = (const float*)d_in[19], *root2 = (const float*)d_in[20], *bias2 = (const float*)d_in[21];
    const float* w_out = (const float*)d_in[22], *b_out = (const float*)d_in[23];
    float* outp = (float*)d_out;

    const int HSZ = HD * HD, PSZ = 768 * 64;

    // ---- workspace carve-up ----
    float* base  = (float*)d_ws;                       // [N,HD] f32
    u16*   hrelb = (u16*)(base + (size_t)NN * HD);     // [2,N,HD] bf16
    u16*   xh    = hrelb + (size_t)2 * NN * HD;
    u16*   xl    = xh + (size_t)NN * HD;
    u16*   yh    = xl + (size_t)NN * HD;
    u16*   yl    = yh + (size_t)NN * HD;
    int*   offs  = (int*)(yl + (size_t)NN * HD);
    int*   segc  = offs + (NSEG + 1);
    int*   srcl  = segc + NSEG;
    int*   bsum  = srcl + EE;
    int*   bbase = bsum + NB;
    uintptr_t wp = ((uintptr_t)(bbase + NB) + 15) & ~(uintptr_t)15;
    u16* desB = (u16*)wp;
    u16* twB  = desB + PSZ;
    u16* winB = twB + PSZ;
    u16* cat1 = winB + HSZ;
    u16* cat2 = cat1 + 3 * HSZ;

    // ---- CSR build ----
    hipMemsetAsync(segc, 0, NSEG * sizeof(int), stream);
    count_seg<<<(EE + 255) / 256, 256, 0, stream>>>(ei, et, segc);
    scan_local<<<NB, 256, 0, stream>>>(segc, offs, bsum);
    scan_bsum<<<1, 64, 0, stream>>>(bsum, bbase);
    add_base<<<(NSEG + 255) / 256, 256, 0, stream>>>(offs, bbase);
    hipMemsetAsync(segc, 0, NSEG * sizeof(int), stream);
    fill_src<<<(EE + 255) / 256, 256, 0, stream>>>(ei, et, offs, segc, srcl);

    // ---- weight RNE+transpose ----
    conv_w<<<(PSZ + 255) / 256, 256, 0, stream>>>(w_des, 768, 64, desB, 0);
    conv_w<<<(PSZ + 255) / 256, 256, 0, stream>>>(w_tw,  768, 64, twB,  0);
    conv_w<<<(HSZ + 255) / 256, 256, 0, stream>>>(w_in, HD, HD, winB, 0);
    conv_w<<<(HSZ + 255) / 256, 256, 0, stream>>>(weight1,       HD, HD, cat1, 0);
    conv_w<<<(HSZ + 255) / 256, 256, 0, stream>>>(weight1 + HSZ, HD, HD, cat1, 256);
    conv_w<<<(HSZ + 255) / 256, 256, 0, stream>>>(root1,         HD, HD, cat1, 512);
    conv_w<<<(HSZ + 255) / 256, 256, 0, stream>>>(weight2,       HD, HD, cat2, 0);
    conv_w<<<(HSZ + 255) / 256, 256, 0, stream>>>(weight2 + HSZ, HD, HD, cat2, 256);
    conv_w<<<(HSZ + 255) / 256, 256, 0, stream>>>(root2,         HD, HD, cat2, 512);

    const int NYB = (NN + 127) / 128;    // 391 (128-row blocks)
    const int NPB = (NN + 63) / 64;      // 782 (64-row blocks)

    // ---- fused feature projections (des+tweet) -> xh/xl ----
    gemm_projP<<<2 * NPB, 256, 0, stream>>>(des, tweet, desB, twB, b_des, b_tw, xh, xl);
    dim3 gsmall(1, (NN + 63) / 64);
    gemm_f32s<64, 64, 8, 4, 4><<<gsmall, 256, 0, stream>>>(nump, 5, w_num, 64, b_num, xh, xl, 128, NN, 64, 5);
    gemm_f32s<64, 64, 8, 4, 4><<<gsmall, 256, 0, stream>>>(catp, 3, w_cat, 64, b_cat, xh, xl, 192, NN, 64, 3);

    // ---- y = lrelu(x @ w_in + b_in) -> yh/yl ----
    gemm_bf16L<1><<<2 * NYB, 256, 0, stream>>>(xh, xl, winB, b_in, yh, yl, nullptr, NN, 2);

    // ---- layer 1: fused [W_r0|W_r1|root1] -> hrelb (bf16) + base (f32) ----
    gemm_bf16L<2><<<6 * NYB, 256, 0, stream>>>(yh, yl, cat1, bias1, hrelb, nullptr, base, NN, 6);
    gather_mean_b<0><<<(NN + 3) / 4, 256, 0, stream>>>(hrelb, offs, srcl, base, xh, xl, nullptr, nullptr, nullptr);

    // ---- layer 2 + fused output head ----
    gemm_bf16L<2><<<6 * NYB, 256, 0, stream>>>(xh, xl, cat2, bias2, hrelb, nullptr, base, NN, 6);
    gather_mean_b<1><<<(NN + 3) / 4, 256, 0, stream>>>(hrelb, offs, srcl, base, nullptr, nullptr, w_out, b_out, outp);
}

// Round 10
// 610.029 us; speedup vs baseline: 1.1895x; 1.0150x over previous
//
#include <hip/hip_runtime.h>

#define NN 50000
#define EE 800000
#define HD 256
#define NSEG (2 * NN)
#define CHUNK 2048
#define NB ((NSEG + CHUNK - 1) / CHUNK)

typedef unsigned short u16;
typedef short bf16x8 __attribute__((ext_vector_type(8)));
typedef float f32x4 __attribute__((ext_vector_type(4)));

__device__ __forceinline__ u16 f2bf_rne(float f) {
    unsigned u = __float_as_uint(f);
    return (u16)((u + 0x7FFF + ((u >> 16) & 1)) >> 16);
}
// trunc hi + RNE residual: (h,l) represents v to ~2^-17 relative
__device__ __forceinline__ void split_tr(float v, u16& h, u16& l) {
    unsigned u = __float_as_uint(v);
    h = (u16)(u >> 16);
    l = f2bf_rne(v - __uint_as_float(u & 0xFFFF0000u));
}

// bijective XCD-chunked swizzle (m204)
__device__ __forceinline__ int xcd_swizzle(int orig, int nwg) {
    int q = nwg >> 3, r = nwg & 7;
    int xcd = orig & 7, idx = orig >> 3;
    return (xcd < r ? xcd * (q + 1) : r * (q + 1) + (xcd - r) * q) + idx;
}

// async global->LDS, 16B per lane; LDS dest = wave-uniform base + lane*16
__device__ __forceinline__ void g2l16(const void* g, void* l) {
    __builtin_amdgcn_global_load_lds(
        (const __attribute__((address_space(1))) void*)g,
        (__attribute__((address_space(3))) void*)l, 16, 0, 0);
}

// bank swizzle for 64B-row bf16 tiles
__device__ __forceinline__ int swz2(int row) { return (row & 2) | ((row >> 2) & 1); }

// stage one 128x32 bf16 tile from G[rc][K] (k-contiguous), source-swizzled
__device__ __forceinline__ void stage_bf16(const u16* __restrict__ G, u16* S,
                                           int base_rc, int maxrc, int K, int k0, int tid) {
#pragma unroll
    for (int s = 0; s < 2; s++) {
        int slot = tid + s * 256;
        int row = slot >> 2, gg = slot & 3;
        int gsrc = gg ^ swz2(row);
        int arow = base_rc + row; arow = arow < maxrc ? arow : maxrc - 1;
        g2l16(G + (size_t)arow * K + k0 + gsrc * 8, S + ((tid & ~63) + s * 256) * 8);
    }
}

// ============ counted-vmcnt dbuf bf16 GEMM: A hi/lo pair [M][256], B bf16 [Ncol][256] ==
// acc = Ah*Bh + Al*Bh. BM=BN=128, 4 waves 2x2, MFMA 16x16x32, k-map k=k0+g*8+j.
// Stage = 6 VMEM instr/thread -> steady-state wait vmcnt(6) keeps next tile in flight.
// MODE 1: lrelu -> bf16 pair out (w_in). MODE 2: relu; col<512 -> bf16 hrel; else f32 O2.
template<int MODE>
__global__ __launch_bounds__(256) void gemm_bf16L(
    const u16* __restrict__ Ahg, const u16* __restrict__ Alg,
    const u16* __restrict__ Bhg,
    const float* __restrict__ bias,
    u16* __restrict__ O1h, u16* __restrict__ O1l, float* __restrict__ O2,
    int M, int nxb)
{
    __shared__ __align__(16) u16 sAh[2][128 * 32];
    __shared__ __align__(16) u16 sAl[2][128 * 32];
    __shared__ __align__(16) u16 sBh[2][128 * 32];
    const int wgid = xcd_swizzle(blockIdx.x, gridDim.x);
    const int brow = (wgid / nxb) * 128, bcol = (wgid % nxb) * 128;
    const int tid = threadIdx.x, lane = tid & 63, w = tid >> 6;
    const int wr = w >> 1, wc = w & 1;
    const int r15 = lane & 15, g = lane >> 4;
    const int fsw = (g ^ swz2(r15)) * 8;

    f32x4 acc[4][4];
#pragma unroll
    for (int mi = 0; mi < 4; mi++)
#pragma unroll
        for (int ni = 0; ni < 4; ni++) acc[mi][ni] = (f32x4){0.f, 0.f, 0.f, 0.f};

    auto stage_step = [&](int k0, int b) {       // 6 VMEM instr per thread
        stage_bf16(Ahg, sAh[b], brow, M, 256, k0, tid);
        stage_bf16(Alg, sAl[b], brow, M, 256, k0, tid);
        stage_bf16(Bhg, sBh[b], bcol, 1 << 30, 256, k0, tid);
    };
    auto compute_step = [&](int b) {
        bf16x8 afh[4], afl[4], bfh[4];
#pragma unroll
        for (int mi = 0; mi < 4; mi++) {
            int idx = (wr * 64 + mi * 16 + r15) * 32 + fsw;
            afh[mi] = *(const bf16x8*)&sAh[b][idx];
            afl[mi] = *(const bf16x8*)&sAl[b][idx];
        }
#pragma unroll
        for (int ni = 0; ni < 4; ni++) {
            int idx = (wc * 64 + ni * 16 + r15) * 32 + fsw;
            bfh[ni] = *(const bf16x8*)&sBh[b][idx];
        }
#pragma unroll
        for (int mi = 0; mi < 4; mi++)
#pragma unroll
            for (int ni = 0; ni < 4; ni++)
                acc[mi][ni] = __builtin_amdgcn_mfma_f32_16x16x32_bf16(afh[mi], bfh[ni], acc[mi][ni], 0, 0, 0);
#pragma unroll
        for (int mi = 0; mi < 4; mi++)
#pragma unroll
            for (int ni = 0; ni < 4; ni++)
                acc[mi][ni] = __builtin_amdgcn_mfma_f32_16x16x32_bf16(afl[mi], bfh[ni], acc[mi][ni], 0, 0, 0);
    };

    stage_step(0, 0);
    stage_step(32, 1);
#pragma unroll
    for (int t = 0; t < 7; t++) {
        asm volatile("s_waitcnt vmcnt(6)" ::: "memory");   // drain buf[t&1] only
        __builtin_amdgcn_s_barrier();
        compute_step(t & 1);
        __builtin_amdgcn_s_barrier();                      // all reads of buf[t&1] retired
        if (t + 2 < 8) stage_step((t + 2) * 32, t & 1);
    }
    asm volatile("s_waitcnt vmcnt(0)" ::: "memory");
    __builtin_amdgcn_s_barrier();
    compute_step(1);

#pragma unroll
    for (int mi = 0; mi < 4; mi++) {
#pragma unroll
        for (int ni = 0; ni < 4; ni++) {
            int col = bcol + wc * 64 + ni * 16 + r15;
            float bsv = bias[col & (HD - 1)];
            int rbase = brow + wr * 64 + mi * 16 + g * 4;
#pragma unroll
            for (int r = 0; r < 4; r++) {
                int grow = rbase + r;
                if (grow >= M) continue;
                float v = acc[mi][ni][r] + bsv;
                if (MODE == 1) {
                    v = v > 0.f ? v : 0.01f * v;   // lrelu
                    u16 h, l; split_tr(v, h, l);
                    O1h[(size_t)grow * HD + col] = h;
                    O1l[(size_t)grow * HD + col] = l;
                } else {
                    v = fmaxf(v, 0.f);             // relu
                    if (col < 2 * HD) {
                        O1h[((size_t)(col >> 8) * NN + grow) * HD + (col & (HD - 1))] = f2bf_rne(v);
                    } else {
                        O2[(size_t)grow * HD + (col & (HD - 1))] = v;
                    }
                }
            }
        }
    }
}

// ============ fused dual-projection GEMM (des & tweet, K=768), counted vmcnt ============
// p = blockIdx&1 selects projection. BM=64, BN=64, 4 waves 2x2 (MI=NI=2).
// Stage = 3 VMEM instr/thread -> steady-state wait vmcnt(3).
__global__ __launch_bounds__(256) void gemm_projP(
    const float* __restrict__ A0, const float* __restrict__ A1,
    const u16* __restrict__ B0, const u16* __restrict__ B1,
    const float* __restrict__ bias0, const float* __restrict__ bias1,
    u16* __restrict__ Ch, u16* __restrict__ Cl)
{
    __shared__ __align__(16) float sA[2][64 * 32];
    __shared__ __align__(16) u16 sB[2][64 * 32];
    const int p = blockIdx.x & 1;
    const int brow = (blockIdx.x >> 1) * 64;
    const float* __restrict__ A = p ? A1 : A0;
    const u16* __restrict__ B = p ? B1 : B0;
    const float* __restrict__ bias = p ? bias1 : bias0;
    const int coff = p * 64;

    const int tid = threadIdx.x, lane = tid & 63, w = tid >> 6;
    const int wr = w >> 1, wc = w & 1;
    const int r15 = lane & 15, g = lane >> 4;
    const int sw8 = r15 & 7;

    f32x4 acc[2][2];
#pragma unroll
    for (int mi = 0; mi < 2; mi++)
#pragma unroll
        for (int ni = 0; ni < 2; ni++) acc[mi][ni] = (f32x4){0.f, 0.f, 0.f, 0.f};

    auto stage_step = [&](int k0, int b) {       // 3 VMEM instr per thread
#pragma unroll
        for (int s = 0; s < 2; s++) {
            int slot = tid + s * 256;
            int row = slot >> 3, cc = slot & 7;
            int csrc = cc ^ (row & 7);
            int arow = brow + row; arow = arow < NN ? arow : NN - 1;
            g2l16(A + (size_t)arow * 768 + k0 + csrc * 4,
                  (u16*)sA[b] + ((tid & ~63) + s * 256) * 8);
        }
        {
            int row = tid >> 2, gg = tid & 3;
            int gsrc = gg ^ swz2(row);
            g2l16(B + (size_t)row * 768 + k0 + gsrc * 8, sB[b] + (tid & ~63) * 8);
        }
    };
    auto compute_step = [&](int b) {
        bf16x8 afh[2], afl[2], bfh[2];
#pragma unroll
        for (int mi = 0; mi < 2; mi++) {
            int lr = wr * 32 + mi * 16 + r15;
            f32x4 v0 = *(const f32x4*)&sA[b][lr * 32 + ((2 * g) ^ sw8) * 4];
            f32x4 v1 = *(const f32x4*)&sA[b][lr * 32 + ((2 * g + 1) ^ sw8) * 4];
            float vf[8] = {v0[0], v0[1], v0[2], v0[3], v1[0], v1[1], v1[2], v1[3]};
#pragma unroll
            for (int j = 0; j < 8; j++) {
                u16 h, l; split_tr(vf[j], h, l);
                afh[mi][j] = (short)h;
                afl[mi][j] = (short)l;
            }
        }
#pragma unroll
        for (int ni = 0; ni < 2; ni++) {
            int idx = (wc * 32 + ni * 16 + r15) * 32 + (g ^ swz2(r15)) * 8;
            bfh[ni] = *(const bf16x8*)&sB[b][idx];
        }
#pragma unroll
        for (int mi = 0; mi < 2; mi++)
#pragma unroll
            for (int ni = 0; ni < 2; ni++)
                acc[mi][ni] = __builtin_amdgcn_mfma_f32_16x16x32_bf16(afh[mi], bfh[ni], acc[mi][ni], 0, 0, 0);
#pragma unroll
        for (int mi = 0; mi < 2; mi++)
#pragma unroll
            for (int ni = 0; ni < 2; ni++)
                acc[mi][ni] = __builtin_amdgcn_mfma_f32_16x16x32_bf16(afl[mi], bfh[ni], acc[mi][ni], 0, 0, 0);
    };

    stage_step(0, 0);
    stage_step(32, 1);
    for (int t = 0; t < 23; t++) {
        asm volatile("s_waitcnt vmcnt(3)" ::: "memory");   // drain buf[t&1] only
        __builtin_amdgcn_s_barrier();
        compute_step(t & 1);
        __builtin_amdgcn_s_barrier();
        if (t + 2 < 24) stage_step((t + 2) * 32, t & 1);
    }
    asm volatile("s_waitcnt vmcnt(0)" ::: "memory");
    __builtin_amdgcn_s_barrier();
    compute_step(1);

#pragma unroll
    for (int mi = 0; mi < 2; mi++) {
#pragma unroll
        for (int ni = 0; ni < 2; ni++) {
            int col = wc * 32 + ni * 16 + r15;
            float bsv = bias[col];
            int rbase = brow + wr * 32 + mi * 16 + g * 4;
#pragma unroll
            for (int r = 0; r < 4; r++) {
                int grow = rbase + r;
                if (grow >= NN) continue;
                float v = acc[mi][ni][r] + bsv;
                v = v > 0.f ? v : 0.01f * v;   // lrelu
                u16 h, l; split_tr(v, h, l);
                Ch[(size_t)grow * HD + coff + col] = h;
                Cl[(size_t)grow * HD + coff + col] = l;
            }
        }
    }
}

// ---- weight RNE-round+transpose: W f32 [K][Ncol] -> T bf16 [colOff+n][K] ----
__global__ void conv_w(const float* __restrict__ W, int K, int Ncol,
                       u16* __restrict__ Th, int colOff)
{
    int i = blockIdx.x * 256 + threadIdx.x;
    if (i >= K * Ncol) return;
    int k = i / Ncol, n = i % Ncol;
    Th[(size_t)(colOff + n) * K + k] = f2bf_rne(W[i]);
}

// ---------------- small f32 GEMM (K=5/3), bf16-pair out ----------------
template<int BM, int BN, int BK, int TM, int TN>
__global__ __launch_bounds__(256) void gemm_f32s(
    const float* __restrict__ A, int lda,
    const float* __restrict__ B, int ldb,
    const float* __restrict__ bias,
    u16* __restrict__ Ch, u16* __restrict__ Cl, int coff,
    int M, int Ncol, int K)
{
    constexpr int TX = BN / TN;
    __shared__ float As[BK][BM + 4];
    __shared__ float Bs[BK][BN + 4];
    const int tid = threadIdx.x;
    const int tx = tid % TX, ty = tid / TX;
    const int brow = blockIdx.y * BM;
    const int bcol = blockIdx.x * BN;
    float acc[TM][TN];
#pragma unroll
    for (int i = 0; i < TM; i++)
#pragma unroll
        for (int j = 0; j < TN; j++) acc[i][j] = 0.f;
    for (int k0 = 0; k0 < K; k0 += BK) {
#pragma unroll
        for (int idx = tid; idx < BM * BK; idx += 256) {
            int m = idx / BK, k = idx % BK;
            int gr = brow + m, gk = k0 + k;
            As[k][m] = (gr < M && gk < K) ? A[(size_t)gr * lda + gk] : 0.f;
        }
#pragma unroll
        for (int idx = tid; idx < BK * BN; idx += 256) {
            int k = idx / BN, n = idx % BN;
            int gk = k0 + k, gc = bcol + n;
            Bs[k][n] = (gk < K && gc < Ncol) ? B[(size_t)gk * ldb + gc] : 0.f;
        }
        __syncthreads();
#pragma unroll
        for (int k = 0; k < BK; k++) {
            float a[TM], b[TN];
#pragma unroll
            for (int i = 0; i < TM; i++) a[i] = As[k][ty * TM + i];
#pragma unroll
            for (int j = 0; j < TN; j++) b[j] = Bs[k][tx * TN + j];
#pragma unroll
            for (int i = 0; i < TM; i++)
#pragma unroll
                for (int j = 0; j < TN; j++) acc[i][j] = fmaf(a[i], b[j], acc[i][j]);
        }
        __syncthreads();
    }
#pragma unroll
    for (int i = 0; i < TM; i++) {
        int gr = brow + ty * TM + i;
        if (gr >= M) continue;
#pragma unroll
        for (int j = 0; j < TN; j++) {
            int gc = bcol + tx * TN + j;
            if (gc >= Ncol) continue;
            float v = acc[i][j] + bias[gc];
            v = v > 0.f ? v : 0.01f * v;
            u16 h, l; split_tr(v, h, l);
            Ch[(size_t)gr * HD + coff + gc] = h;
            Cl[(size_t)gr * HD + coff + gc] = l;
        }
    }
}

// ---------------- CSR build ----------------
__global__ void count_seg(const int* __restrict__ ei, const int* __restrict__ et,
                          int* __restrict__ segc)
{
    int e = blockIdx.x * blockDim.x + threadIdx.x;
    if (e < EE) {
        int dst = ei[EE + e];
        int r = et[e];
        atomicAdd(&segc[r * NN + dst], 1);
    }
}

__global__ __launch_bounds__(256) void scan_local(const int* __restrict__ segc,
                                                  int* __restrict__ offs,
                                                  int* __restrict__ bsum)
{
    int b = blockIdx.x;
    int base = b * CHUNK;
    int tid = threadIdx.x;
    int lane = tid & 63, wave = tid >> 6;
    __shared__ int wsum[4];
    int vals[8];
    int i0 = base + tid * 8;
    int s = 0;
    if (i0 + 7 < NSEG) {
        int4 v0 = *(const int4*)&segc[i0];
        int4 v1 = *(const int4*)&segc[i0 + 4];
        vals[0] = v0.x; vals[1] = v0.y; vals[2] = v0.z; vals[3] = v0.w;
        vals[4] = v1.x; vals[5] = v1.y; vals[6] = v1.z; vals[7] = v1.w;
    } else {
#pragma unroll
        for (int j = 0; j < 8; j++) vals[j] = (i0 + j < NSEG) ? segc[i0 + j] : 0;
    }
#pragma unroll
    for (int j = 0; j < 8; j++) s += vals[j];
    int v = s;
#pragma unroll
    for (int off = 1; off < 64; off <<= 1) {
        int u = __shfl_up(v, off);
        if (lane >= off) v += u;
    }
    if (lane == 63) wsum[wave] = v;
    __syncthreads();
    int wbase = 0;
#pragma unroll
    for (int ww = 0; ww < 4; ww++) if (ww < wave) wbase += wsum[ww];
    int run = wbase + v - s;
#pragma unroll
    for (int j = 0; j < 8; j++) {
        run += vals[j];
        int i = i0 + j;
        if (i < NSEG) offs[i + 1] = run;
    }
    if (tid == 0) {
        int t = 0;
#pragma unroll
        for (int ww = 0; ww < 4; ww++) t += wsum[ww];
        bsum[b] = t;
    }
}

__global__ void scan_bsum(const int* __restrict__ bsum, int* __restrict__ bbase)
{
    int lane = threadIdx.x;
    int c = (lane < NB) ? bsum[lane] : 0;
    int v = c;
#pragma unroll
    for (int off = 1; off < 64; off <<= 1) {
        int u = __shfl_up(v, off);
        if (lane >= off) v += u;
    }
    if (lane < NB) bbase[lane] = v - c;
}

__global__ void add_base(int* __restrict__ offs, const int* __restrict__ bbase)
{
    int i = blockIdx.x * blockDim.x + threadIdx.x;
    if (i < NSEG) offs[i + 1] += bbase[i / CHUNK];
    if (i == 0) offs[0] = 0;
}

__global__ void fill_src(const int* __restrict__ ei, const int* __restrict__ et,
                         const int* __restrict__ offs, int* __restrict__ cursor,
                         int* __restrict__ src_list)
{
    int e = blockIdx.x * blockDim.x + threadIdx.x;
    if (e < EE) {
        int src = ei[e];
        int dst = ei[EE + e];
        int s = et[e] * NN + dst;
        int pos = offs[s] + atomicAdd(&cursor[s], 1);
        src_list[pos] = src;
    }
}

// ---------------- gather: v = base + sum_r mean(hrel_bf16) ----------------
// OUTM 0: write bf16 hi/lo pair (next layer input).
// OUTM 1: fused head: logits[d,c] = v . w_out[:,c] + b_out[c]
template<int OUTM>
__global__ __launch_bounds__(256) void gather_mean_b(
    const u16* __restrict__ hrelb,
    const int* __restrict__ offs,
    const int* __restrict__ src_list,
    const float* __restrict__ basein,
    u16* __restrict__ Oh, u16* __restrict__ Ol,
    const float* __restrict__ wout, const float* __restrict__ bout,
    float* __restrict__ logits)
{
    int d = blockIdx.x * 4 + (threadIdx.x >> 6);
    if (d >= NN) return;
    int lane = threadIdx.x & 63;
    f32x4 acc = {0.f, 0.f, 0.f, 0.f};
#pragma unroll
    for (int r = 0; r < 2; r++) {
        int s = r * NN + d;
        int start = offs[s], end = offs[s + 1];
        if (start == end) continue;
        f32x4 a = {0.f, 0.f, 0.f, 0.f};
        const u16* hb = hrelb + (size_t)r * NN * HD;
        for (int i = start; i < end; i++) {
            int src = src_list[i];
            uint2 wv = *(const uint2*)(hb + (size_t)src * HD + lane * 4);
            a.x += __uint_as_float(wv.x << 16);
            a.y += __uint_as_float(wv.x & 0xFFFF0000u);
            a.z += __uint_as_float(wv.y << 16);
            a.w += __uint_as_float(wv.y & 0xFFFF0000u);
        }
        float inv = 1.0f / (float)(end - start);
        acc.x += a.x * inv; acc.y += a.y * inv;
        acc.z += a.z * inv; acc.w += a.w * inv;
    }
    float4 b = ((const float4*)(basein + (size_t)d * HD))[lane];
    float v0 = b.x + acc.x, v1 = b.y + acc.y, v2 = b.z + acc.z, v3 = b.w + acc.w;
    if (OUTM == 0) {
        u16 h0, l0, h1, l1, h2, l2, h3, l3;
        split_tr(v0, h0, l0); split_tr(v1, h1, l1);
        split_tr(v2, h2, l2); split_tr(v3, h3, l3);
        uint2 uh, ul;
        uh.x = (unsigned)h0 | ((unsigned)h1 << 16);
        uh.y = (unsigned)h2 | ((unsigned)h3 << 16);
        ul.x = (unsigned)l0 | ((unsigned)l1 << 16);
        ul.y = (unsigned)l2 | ((unsigned)l3 << 16);
        *(uint2*)(Oh + (size_t)d * HD + lane * 4) = uh;
        *(uint2*)(Ol + (size_t)d * HD + lane * 4) = ul;
    } else {
        int k = lane * 4;
        float a0 = v0 * wout[(k + 0) * 2 + 0] + v1 * wout[(k + 1) * 2 + 0]
                 + v2 * wout[(k + 2) * 2 + 0] + v3 * wout[(k + 3) * 2 + 0];
        float a1 = v0 * wout[(k + 0) * 2 + 1] + v1 * wout[(k + 1) * 2 + 1]
                 + v2 * wout[(k + 2) * 2 + 1] + v3 * wout[(k + 3) * 2 + 1];
#pragma unroll
        for (int off = 32; off > 0; off >>= 1) {
            a0 += __shfl_down(a0, off);
            a1 += __shfl_down(a1, off);
        }
        if (lane == 0) {
            logits[(size_t)d * 2 + 0] = a0 + bout[0];
            logits[(size_t)d * 2 + 1] = a1 + bout[1];
        }
    }
}

extern "C" void kernel_launch(void* const* d_in, const int* in_sizes, int n_in,
                              void* d_out, int out_size, void* d_ws, size_t ws_size,
                              hipStream_t stream)
{
    const float* des   = (const float*)d_in[0];
    const float* tweet = (const float*)d_in[1];
    const float* nump  = (const float*)d_in[2];
    const float* catp  = (const float*)d_in[3];
    const int*   ei    = (const int*)d_in[4];
    const int*   et    = (const int*)d_in[5];
    const float* w_des = (const float*)d_in[6],  *b_des = (const float*)d_in[7];
    const float* w_tw  = (const float*)d_in[8],  *b_tw  = (const float*)d_in[9];
    const float* w_num = (const float*)d_in[10], *b_num = (const float*)d_in[11];
    const float* w_cat = (const float*)d_in[12], *b_cat = (const float*)d_in[13];
    const float* w_in  = (const float*)d_in[14], *b_in  = (const float*)d_in[15];
    const float* weight1 = (const float*)d_in[16], *root1 = (const float*)d_in[17], *bias1 = (const float*)d_in[18];
    const float* weight2 = (const float*)d_in[19], *root2 = (const float*)d_in[20], *bias2 = (const float*)d_in[21];
    const float* w_out = (const float*)d_in[22], *b_out = (const float*)d_in[23];
    float* outp = (float*)d_out;

    const int HSZ = HD * HD, PSZ = 768 * 64;

    // ---- workspace carve-up ----
    float* base  = (float*)d_ws;                       // [N,HD] f32
    u16*   hrelb = (u16*)(base + (size_t)NN * HD);     // [2,N,HD] bf16
    u16*   xh    = hrelb + (size_t)2 * NN * HD;
    u16*   xl    = xh + (size_t)NN * HD;
    u16*   yh    = xl + (size_t)NN * HD;
    u16*   yl    = yh + (size_t)NN * HD;
    int*   offs  = (int*)(yl + (size_t)NN * HD);
    int*   segc  = offs + (NSEG + 1);
    int*   srcl  = segc + NSEG;
    int*   bsum  = srcl + EE;
    int*   bbase = bsum + NB;
    uintptr_t wp = ((uintptr_t)(bbase + NB) + 15) & ~(uintptr_t)15;
    u16* desB = (u16*)wp;
    u16* twB  = desB + PSZ;
    u16* winB = twB + PSZ;
    u16* cat1 = winB + HSZ;
    u16* cat2 = cat1 + 3 * HSZ;

    // ---- CSR build ----
    hipMemsetAsync(segc, 0, NSEG * sizeof(int), stream);
    count_seg<<<(EE + 255) / 256, 256, 0, stream>>>(ei, et, segc);
    scan_local<<<NB, 256, 0, stream>>>(segc, offs, bsum);
    scan_bsum<<<1, 64, 0, stream>>>(bsum, bbase);
    add_base<<<(NSEG + 255) / 256, 256, 0, stream>>>(offs, bbase);
    hipMemsetAsync(segc, 0, NSEG * sizeof(int), stream);
    fill_src<<<(EE + 255) / 256, 256, 0, stream>>>(ei, et, offs, segc, srcl);

    // ---- weight RNE+transpose ----
    conv_w<<<(PSZ + 255) / 256, 256, 0, stream>>>(w_des, 768, 64, desB, 0);
    conv_w<<<(PSZ + 255) / 256, 256, 0, stream>>>(w_tw,  768, 64, twB,  0);
    conv_w<<<(HSZ + 255) / 256, 256, 0, stream>>>(w_in, HD, HD, winB, 0);
    conv_w<<<(HSZ + 255) / 256, 256, 0, stream>>>(weight1,       HD, HD, cat1, 0);
    conv_w<<<(HSZ + 255) / 256, 256, 0, stream>>>(weight1 + HSZ, HD, HD, cat1, 256);
    conv_w<<<(HSZ + 255) / 256, 256, 0, stream>>>(root1,         HD, HD, cat1, 512);
    conv_w<<<(HSZ + 255) / 256, 256, 0, stream>>>(weight2,       HD, HD, cat2, 0);
    conv_w<<<(HSZ + 255) / 256, 256, 0, stream>>>(weight2 + HSZ, HD, HD, cat2, 256);
    conv_w<<<(HSZ + 255) / 256, 256, 0, stream>>>(root2,         HD, HD, cat2, 512);

    const int NYB = (NN + 127) / 128;    // 391 (128-row blocks)
    const int NPB = (NN + 63) / 64;      // 782 (64-row blocks)

    // ---- fused feature projections (des+tweet) -> xh/xl ----
    gemm_projP<<<2 * NPB, 256, 0, stream>>>(des, tweet, desB, twB, b_des, b_tw, xh, xl);
    dim3 gsmall(1, (NN + 63) / 64);
    gemm_f32s<64, 64, 8, 4, 4><<<gsmall, 256, 0, stream>>>(nump, 5, w_num, 64, b_num, xh, xl, 128, NN, 64, 5);
    gemm_f32s<64, 64, 8, 4, 4><<<gsmall, 256, 0, stream>>>(catp, 3, w_cat, 64, b_cat, xh, xl, 192, NN, 64, 3);

    // ---- y = lrelu(x @ w_in + b_in) -> yh/yl ----
    gemm_bf16L<1><<<2 * NYB, 256, 0, stream>>>(xh, xl, winB, b_in, yh, yl, nullptr, NN, 2);

    // ---- layer 1: fused [W_r0|W_r1|root1] -> hrelb (bf16) + base (f32) ----
    gemm_bf16L<2><<<6 * NYB, 256, 0, stream>>>(yh, yl, cat1, bias1, hrelb, nullptr, base, NN, 6);
    gather_mean_b<0><<<(NN + 3) / 4, 256, 0, stream>>>(hrelb, offs, srcl, base, xh, xl, nullptr, nullptr, nullptr);

    // ---- layer 2 + fused output head ----
    gemm_bf16L<2><<<6 * NYB, 256, 0, stream>>>(xh, xl, cat2, bias2, hrelb, nullptr, base, NN, 6);
    gather_mean_b<1><<<(NN + 3) / 4, 256, 0, stream>>>(hrelb, offs, srcl, base, nullptr, nullptr, w_out, b_out, outp);
}